// Round 8
// baseline (247.643 us; speedup 1.0000x reference)
//
#include <hip/hip_runtime.h>
#include <hip/hip_bf16.h>
#include <math.h>

// Problem constants: B=4, N=2048, C=768, H=12, D=64
#define BATCH 4
#define SEQ   2048
#define CDIM  768
#define NHEAD 12
#define HDIM  64
#define MROWS (BATCH*SEQ)      // 8192
#define QKVC  (3*CDIM)         // 2304

typedef __bf16    bf16x8 __attribute__((ext_vector_type(8)));
typedef _Float16  f16x8  __attribute__((ext_vector_type(8)));
typedef _Float16  f16x4  __attribute__((ext_vector_type(4)));
typedef float     f32x4  __attribute__((ext_vector_type(4)));

__device__ __forceinline__ void async16(const void* g, void* l) {
  __builtin_amdgcn_global_load_lds(
      (const __attribute__((address_space(1))) void*)g,
      (__attribute__((address_space(3))) void*)l, 16, 0, 0);
}

// ---------------------------------------------------------------------------
// Elementwise fp32 -> bf16 cast, 8 elems/thread.
// ---------------------------------------------------------------------------
__global__ __launch_bounds__(256) void cast_f32_bf16(
    const float* __restrict__ in, __bf16* __restrict__ out, int n8) {
  int i = blockIdx.x * 256 + threadIdx.x;
  if (i >= n8) return;
  float4 a = reinterpret_cast<const float4*>(in)[i * 2];
  float4 b = reinterpret_cast<const float4*>(in)[i * 2 + 1];
  bf16x8 o;
  o[0] = (__bf16)a.x; o[1] = (__bf16)a.y; o[2] = (__bf16)a.z; o[3] = (__bf16)a.w;
  o[4] = (__bf16)b.x; o[5] = (__bf16)b.y; o[6] = (__bf16)b.z; o[7] = (__bf16)b.w;
  reinterpret_cast<bf16x8*>(out)[i] = o;
}

// ---------------------------------------------------------------------------
// Transpose-cast: w [K,N] fp32 -> wT [N,K] bf16. 32x32 LDS tile.
// ---------------------------------------------------------------------------
__global__ __launch_bounds__(256) void transpose_cast(
    const float* __restrict__ w, __bf16* __restrict__ wt, int K, int N) {
  __shared__ float sh[32][33];
  const int n0 = blockIdx.x * 32, k0 = blockIdx.y * 32;
  const int tx = threadIdx.x, ty = threadIdx.y;  // 32 x 8
#pragma unroll
  for (int i = 0; i < 4; ++i)
    sh[ty + i * 8][tx] = w[(size_t)(k0 + ty + i * 8) * N + n0 + tx];
  __syncthreads();
#pragma unroll
  for (int i = 0; i < 4; ++i)
    wt[(size_t)(n0 + ty + i * 8) * K + k0 + tx] = (__bf16)sh[tx][ty + i * 8];
}

// ---------------------------------------------------------------------------
// BF16 MFMA GEMM (m97 structure): C[M,N] = A[M,K] @ B[K,N], B given as
// Bt[N,K]. 128x128 tile, BK=32, 4 waves (2x2). Epilogue bf16 or fp32+bias.
// ---------------------------------------------------------------------------
template <bool BF16OUT>
__global__ __launch_bounds__(256) void gemm_bf16_kernel(
    const __bf16* __restrict__ A, const __bf16* __restrict__ Bt,
    const float* __restrict__ bias, void* __restrict__ Cout,
    int M, int N, int K) {
  __shared__ __align__(16) __bf16 As[128 * 32];
  __shared__ __align__(16) __bf16 Bs[128 * 32];
  const int tid  = threadIdx.x;
  const int w    = tid >> 6;
  const int lane = tid & 63;
  const int quad = lane >> 4;
  const int lr   = lane & 15;
  const int wr   = w >> 1, wc = w & 1;
  const int mBase = blockIdx.y * 128, nBase = blockIdx.x * 128;

  f32x4 acc[4][4] = {};

  const int srow = lane >> 2;
  const int sk8  = (lane & 3) * 8;
  const __bf16* aSrc0 = A  + (size_t)(mBase + w * 32 + srow) * K + sk8;
  const __bf16* aSrc1 = aSrc0 + (size_t)16 * K;
  const __bf16* bSrc0 = Bt + (size_t)(nBase + w * 32 + srow) * K + sk8;
  const __bf16* bSrc1 = bSrc0 + (size_t)16 * K;
  __bf16* aDst0 = &As[(w * 32 + 0) * 32];
  __bf16* aDst1 = &As[(w * 32 + 16) * 32];
  __bf16* bDst0 = &Bs[(w * 32 + 0) * 32];
  __bf16* bDst1 = &Bs[(w * 32 + 16) * 32];

  for (int k0 = 0; k0 < K; k0 += 32) {
    __syncthreads();
    async16(aSrc0 + k0, aDst0);
    async16(aSrc1 + k0, aDst1);
    async16(bSrc0 + k0, bDst0);
    async16(bSrc1 + k0, bDst1);
    __syncthreads();

    bf16x8 af[4], bfr[4];
#pragma unroll
    for (int mt = 0; mt < 4; ++mt)
      af[mt] = *reinterpret_cast<const bf16x8*>(
          &As[(wr * 64 + mt * 16 + lr) * 32 + quad * 8]);
#pragma unroll
    for (int nt = 0; nt < 4; ++nt)
      bfr[nt] = *reinterpret_cast<const bf16x8*>(
          &Bs[(wc * 64 + nt * 16 + lr) * 32 + quad * 8]);
#pragma unroll
    for (int mt = 0; mt < 4; ++mt)
#pragma unroll
      for (int nt = 0; nt < 4; ++nt)
        acc[mt][nt] = __builtin_amdgcn_mfma_f32_16x16x32_bf16(
            af[mt], bfr[nt], acc[mt][nt], 0, 0, 0);
  }

#pragma unroll
  for (int mt = 0; mt < 4; ++mt) {
#pragma unroll
    for (int nt = 0; nt < 4; ++nt) {
      const int col = nBase + wc * 64 + nt * 16 + lr;
#pragma unroll
      for (int r = 0; r < 4; ++r) {
        const size_t row = (size_t)(mBase + wr * 64 + mt * 16 + quad * 4 + r);
        if (BF16OUT) {
          ((__bf16*)Cout)[row * N + col] = (__bf16)acc[mt][nt][r];
        } else {
          ((float*)Cout)[row * N + col] = acc[mt][nt][r] + bias[col];
        }
      }
    }
  }
}

// ---------------------------------------------------------------------------
// Swizzle K and V into fragment-linear global layouts (per (bh, kt) 64-key
// tile), so flash can load MFMA operands with coalesced b128 reads:
//  kF[(hb*32+kt)*8 + f][lane][j]  (bf16) f=nt*2+kc:
//      K[key=nt*16+(lane&15)][d=kc*32+(lane>>4)*8+j]      (A-frag, 16x16x32)
//  vF[(hb*32+kt)*8 + g][lane][j]  (f16)  g=nt*2+ph, j=0..7:
//      V[key=nt*16+(lane>>4)*4+(j&3)][d=(ph*2+(j>>2))*16+(lane&15)] (B-frags)
// ---------------------------------------------------------------------------
__global__ __launch_bounds__(256) void swizzle_kv(
    const __bf16* __restrict__ qkv, __bf16* __restrict__ kF,
    _Float16* __restrict__ vF) {
  const int kt = blockIdx.x;   // 0..31
  const int hb = blockIdx.y;   // 0..47
  const int h = hb % NHEAD, b = hb / NHEAD;
  const int tid = threadIdx.x;

  __shared__ __align__(16) __bf16 Ksh[64][72];   // row stride 144B (16B-mult)
  __shared__ __align__(16) _Float16 Vsh[64][72];

  const int sr = tid >> 3;          // 0..31
  const int sc = (tid & 7) * 8;     // 0,8,..56
  const __bf16* kbase = qkv + (size_t)(b * SEQ + kt * 64) * QKVC + CDIM + h * HDIM;
  const __bf16* vbase = kbase + CDIM;

#pragma unroll
  for (int rr = 0; rr < 2; ++rr) {
    const int row = sr + rr * 32;
    bf16x8 kv = *reinterpret_cast<const bf16x8*>(kbase + (size_t)row * QKVC + sc);
    *reinterpret_cast<bf16x8*>(&Ksh[row][sc]) = kv;
    bf16x8 vv = *reinterpret_cast<const bf16x8*>(vbase + (size_t)row * QKVC + sc);
    f16x8 vf;
#pragma unroll
    for (int j = 0; j < 8; ++j) vf[j] = (_Float16)(float)vv[j];
    *reinterpret_cast<f16x8*>(&Vsh[row][sc]) = vf;
  }
  __syncthreads();

  const size_t tileOff = ((size_t)(hb * 32 + kt)) * 4096;

#pragma unroll
  for (int ss = 0; ss < 2; ++ss) {
    const int s = tid + ss * 256;
    const int f = s >> 6, lane = s & 63;
    const int nt = f >> 1, kc = f & 1;
    const int lq = lane >> 4, ll = lane & 15;
    bf16x8 frag = *reinterpret_cast<const bf16x8*>(
        &Ksh[nt * 16 + ll][kc * 32 + lq * 8]);
    *reinterpret_cast<bf16x8*>(&kF[tileOff + (size_t)f * 512 + lane * 8]) = frag;
  }
#pragma unroll
  for (int ss = 0; ss < 2; ++ss) {
    const int s = tid + ss * 256;
    const int g = s >> 6, lane = s & 63;
    const int nt = g >> 1, ph = g & 1;
    const int lq = lane >> 4, ll = lane & 15;
    f16x8 frag;
#pragma unroll
    for (int j = 0; j < 8; ++j)
      frag[j] = Vsh[nt * 16 + lq * 4 + (j & 3)][(ph * 2 + (j >> 2)) * 16 + ll];
    *reinterpret_cast<f16x8*>(&vF[tileOff + (size_t)g * 512 + lane * 8]) = frag;
  }
}

// ---------------------------------------------------------------------------
// Flash attention, k-split x4. One BLOCK per (hb, q-tile); wave w handles
// k-tiles w, w+4, ... (no-max softmax is linear in k-tiles, so partial (O,l)
// combine by pure addition). Register pipeline identical to R7 (LDS-free per
// k-tile, pre-swizzled kF/vF frags, S^T trick, MFMA row-sum). End-of-block:
// 2-round LDS tree reduction (f32, b128 conflict-free), wave 0 normalizes
// and stores. Blocks XCD-clustered (bid&7), longest-qt-first per XCD.
// ---------------------------------------------------------------------------
__global__ __launch_bounds__(256, 3) void flash_mfma_kernel(
    const __bf16* __restrict__ qkv, const __bf16* __restrict__ kF,
    const _Float16* __restrict__ vF, __bf16* __restrict__ out) {
  const int bid  = blockIdx.x;     // 1536 blocks
  const int tid  = threadIdx.x;
  const int w    = tid >> 6;
  const int lane = tid & 63;
  const int quad = lane >> 4;
  const int lr   = lane & 15;

  const int x   = bid & 7;         // XCD (dispatch round-robins %8)
  const int g   = bid >> 3;        // 0..191
  const int qt  = 31 - (g / 6);    // longest-first within each XCD
  const int hb  = x * 6 + (g % 6);
  const int h   = hb % NHEAD, b = hb / NHEAD;

  __shared__ __align__(16) float Red[2][64 * 80];  // 2 x 20 KB partial bufs

  // ---- Q B-frags (64 q), scale = D^-0.5 * log2(e) ----
  bf16x8 qf[4][2];
  {
    const float qs = 0.125f * 1.44269504088896f;
    const __bf16* qp = qkv + (size_t)(b * SEQ + qt * 64) * QKVC + h * HDIM;
#pragma unroll
    for (int qg = 0; qg < 4; ++qg)
#pragma unroll
      for (int kc = 0; kc < 2; ++kc) {
        bf16x8 qr = *reinterpret_cast<const bf16x8*>(
            qp + (size_t)(qg * 16 + lr) * QKVC + kc * 32 + quad * 8);
        bf16x8 f;
#pragma unroll
        for (int j = 0; j < 8; ++j) f[j] = (__bf16)((float)qr[j] * qs);
        qf[qg][kc] = f;
      }
  }

  f32x4 O[4][4] = {};   // [qg][dt], D-layout: row(quad*4+r)=q_lo, col(lr)=d_lo
  f32x4 O4[4] = {};     // row-sums l per qg, same row layout

  const __bf16*   kT = kF + ((size_t)(hb * 32)) * 4096 + lane * 8;
  const _Float16* vT = vF + ((size_t)(hb * 32)) * 4096 + lane * 8;
  const f16x4 vones = {(_Float16)1.f, (_Float16)1.f, (_Float16)1.f, (_Float16)1.f};

  for (int kt = w; kt <= qt; kt += 4) {
    bf16x8 kf[8];
    f16x8  vf8[8];
#pragma unroll
    for (int f = 0; f < 8; ++f)
      kf[f] = *reinterpret_cast<const bf16x8*>(kT + (size_t)kt * 4096 + f * 512);
#pragma unroll
    for (int gg = 0; gg < 8; ++gg)
      vf8[gg] = *reinterpret_cast<const f16x8*>(vT + (size_t)kt * 4096 + gg * 512);

#pragma unroll
    for (int nt = 0; nt < 4; ++nt) {
      f32x4 s[4];
#pragma unroll
      for (int qg = 0; qg < 4; ++qg) {
        f32x4 acc = (f32x4){0.f, 0.f, 0.f, 0.f};
        acc = __builtin_amdgcn_mfma_f32_16x16x32_bf16(kf[nt * 2 + 0], qf[qg][0], acc, 0, 0, 0);
        acc = __builtin_amdgcn_mfma_f32_16x16x32_bf16(kf[nt * 2 + 1], qf[qg][1], acc, 0, 0, 0);
        s[qg] = acc;
      }
      if (kt == qt) {  // diagonal tile: causal mask
#pragma unroll
        for (int qg = 0; qg < 4; ++qg)
#pragma unroll
          for (int r = 0; r < 4; ++r)
            if (nt * 16 + quad * 4 + r > qg * 16 + lr) s[qg][r] = -1e30f;
      }
      f16x4 pa[4];
#pragma unroll
      for (int qg = 0; qg < 4; ++qg) {
        f16x4 t;
#pragma unroll
        for (int r = 0; r < 4; ++r)
          t[r] = (_Float16)__builtin_amdgcn_exp2f(s[qg][r]);
        pa[qg] = t;
      }
#pragma unroll
      for (int qg = 0; qg < 4; ++qg)
        O4[qg] = __builtin_amdgcn_mfma_f32_16x16x16f16(pa[qg], vones, O4[qg], 0, 0, 0);
#pragma unroll
      for (int dt = 0; dt < 4; ++dt) {
        const f16x8 vv = vf8[nt * 2 + (dt >> 1)];
        f16x4 vb;
#pragma unroll
        for (int j = 0; j < 4; ++j) vb[j] = vv[(dt & 1) * 4 + j];
#pragma unroll
        for (int qg = 0; qg < 4; ++qg)
          O[qg][dt] = __builtin_amdgcn_mfma_f32_16x16x16f16(pa[qg], vb, O[qg][dt], 0, 0, 0);
      }
    }
  }

  // ---- 2-round additive reduction: 20 f32x4 per lane (16 O + 4 O4) ----
  // Round 1: waves 1,3 write; waves 0,2 add.
  if (w == 1 || w == 3) {
    float* dst = Red[w >> 1];
#pragma unroll
    for (int qg = 0; qg < 4; ++qg)
#pragma unroll
      for (int dt = 0; dt < 4; ++dt)
        *reinterpret_cast<f32x4*>(&dst[((qg * 4 + dt) * 64 + lane) * 4]) = O[qg][dt];
#pragma unroll
    for (int qg = 0; qg < 4; ++qg)
      *reinterpret_cast<f32x4*>(&dst[((16 + qg) * 64 + lane) * 4]) = O4[qg];
  }
  __syncthreads();
  if (w == 0 || w == 2) {
    const float* src = Red[w >> 1];
#pragma unroll
    for (int qg = 0; qg < 4; ++qg)
#pragma unroll
      for (int dt = 0; dt < 4; ++dt)
        O[qg][dt] += *reinterpret_cast<const f32x4*>(&src[((qg * 4 + dt) * 64 + lane) * 4]);
#pragma unroll
    for (int qg = 0; qg < 4; ++qg)
      O4[qg] += *reinterpret_cast<const f32x4*>(&src[((16 + qg) * 64 + lane) * 4]);
  }
  __syncthreads();
  // Round 2: wave 2 writes; wave 0 adds.
  if (w == 2) {
    float* dst = Red[0];
#pragma unroll
    for (int qg = 0; qg < 4; ++qg)
#pragma unroll
      for (int dt = 0; dt < 4; ++dt)
        *reinterpret_cast<f32x4*>(&dst[((qg * 4 + dt) * 64 + lane) * 4]) = O[qg][dt];
#pragma unroll
    for (int qg = 0; qg < 4; ++qg)
      *reinterpret_cast<f32x4*>(&dst[((16 + qg) * 64 + lane) * 4]) = O4[qg];
  }
  __syncthreads();
  if (w == 0) {
    const float* src = Red[0];
#pragma unroll
    for (int qg = 0; qg < 4; ++qg)
#pragma unroll
      for (int dt = 0; dt < 4; ++dt)
        O[qg][dt] += *reinterpret_cast<const f32x4*>(&src[((qg * 4 + dt) * 64 + lane) * 4]);
#pragma unroll
    for (int qg = 0; qg < 4; ++qg)
      O4[qg] += *reinterpret_cast<const f32x4*>(&src[((16 + qg) * 64 + lane) * 4]);

    // ---- epilogue: O/l, store bf16 ----
    __bf16* obase = out + (size_t)(b * SEQ + qt * 64) * CDIM + h * HDIM;
#pragma unroll
    for (int qg = 0; qg < 4; ++qg) {
      float linv[4];
#pragma unroll
      for (int r = 0; r < 4; ++r) linv[r] = 1.f / O4[qg][r];
#pragma unroll
      for (int dt = 0; dt < 4; ++dt)
#pragma unroll
        for (int r = 0; r < 4; ++r)
          obase[(size_t)(qg * 16 + quad * 4 + r) * CDIM + dt * 16 + lr] =
              (__bf16)(O[qg][dt][r] * linv[r]);
    }
  }
}

// ---------------------------------------------------------------------------
extern "C" void kernel_launch(void* const* d_in, const int* in_sizes, int n_in,
                              void* d_out, int out_size, void* d_ws, size_t ws_size,
                              hipStream_t stream) {
  const float* x      = (const float*)d_in[0];
  const float* w_qkv  = (const float*)d_in[1];
  const float* w_proj = (const float*)d_in[2];
  const float* b_proj = (const float*)d_in[3];
  float* out = (float*)d_out;

  __bf16* qkv    = (__bf16*)d_ws;                       // [8192,2304]
  __bf16* attnb  = qkv + (size_t)MROWS * QKVC;          // [8192,768]
  __bf16* xb     = attnb + (size_t)MROWS * CDIM;        // [8192,768]
  __bf16* wqkvT  = xb + (size_t)MROWS * CDIM;           // [2304,768]
  __bf16* wprojT = wqkvT + (size_t)QKVC * CDIM;         // [768,768]
  __bf16* kFb    = wprojT + (size_t)CDIM * CDIM;        // [48*32*4096] bf16
  _Float16* vFb  = (_Float16*)(kFb + (size_t)48 * 32 * 4096);  // same size f16

  cast_f32_bf16<<<dim3((MROWS * CDIM / 8 + 255) / 256), dim3(256), 0, stream>>>(
      x, xb, MROWS * CDIM / 8);
  transpose_cast<<<dim3(QKVC / 32, CDIM / 32), dim3(32, 8), 0, stream>>>(
      w_qkv, wqkvT, CDIM, QKVC);
  transpose_cast<<<dim3(CDIM / 32, CDIM / 32), dim3(32, 8), 0, stream>>>(
      w_proj, wprojT, CDIM, CDIM);

  // 1) QKV projection (bf16 MFMA, bf16 out)
  gemm_bf16_kernel<true><<<dim3(QKVC / 128, MROWS / 128), dim3(256), 0, stream>>>(
      xb, wqkvT, nullptr, qkv, MROWS, QKVC, CDIM);

  // 1b) K/V fragment swizzle for flash
  swizzle_kv<<<dim3(32, 48), dim3(256), 0, stream>>>(qkv, kFb, vFb);

  // 2) causal flash attention (k-split x4, additive reduction)
  flash_mfma_kernel<<<dim3(1536), dim3(256), 0, stream>>>(qkv, kFb, vFb, attnb);

  // 3) output projection (bf16 MFMA, fp32 + bias out)
  gemm_bf16_kernel<false><<<dim3(CDIM / 128, MROWS / 128), dim3(256), 0, stream>>>(
      attnb, wprojT, b_proj, out, MROWS, CDIM, CDIM);
}

// Round 9
// 208.785 us; speedup vs baseline: 1.1861x; 1.1861x over previous
//
#include <hip/hip_runtime.h>
#include <hip/hip_bf16.h>
#include <math.h>

// Problem constants: B=4, N=2048, C=768, H=12, D=64
#define BATCH 4
#define SEQ   2048
#define CDIM  768
#define NHEAD 12
#define HDIM  64
#define MROWS (BATCH*SEQ)      // 8192
#define QKVC  (3*CDIM)         // 2304

typedef __bf16    bf16x8 __attribute__((ext_vector_type(8)));
typedef _Float16  f16x8  __attribute__((ext_vector_type(8)));
typedef _Float16  f16x4  __attribute__((ext_vector_type(4)));
typedef float     f32x4  __attribute__((ext_vector_type(4)));

__device__ __forceinline__ void async16(const void* g, void* l) {
  __builtin_amdgcn_global_load_lds(
      (const __attribute__((address_space(1))) void*)g,
      (__attribute__((address_space(3))) void*)l, 16, 0, 0);
}

// ---------------------------------------------------------------------------
// Elementwise fp32 -> bf16 cast, 8 elems/thread.
// ---------------------------------------------------------------------------
__global__ __launch_bounds__(256) void cast_f32_bf16(
    const float* __restrict__ in, __bf16* __restrict__ out, int n8) {
  int i = blockIdx.x * 256 + threadIdx.x;
  if (i >= n8) return;
  float4 a = reinterpret_cast<const float4*>(in)[i * 2];
  float4 b = reinterpret_cast<const float4*>(in)[i * 2 + 1];
  bf16x8 o;
  o[0] = (__bf16)a.x; o[1] = (__bf16)a.y; o[2] = (__bf16)a.z; o[3] = (__bf16)a.w;
  o[4] = (__bf16)b.x; o[5] = (__bf16)b.y; o[6] = (__bf16)b.z; o[7] = (__bf16)b.w;
  reinterpret_cast<bf16x8*>(out)[i] = o;
}

// ---------------------------------------------------------------------------
// Transpose-cast: w [K,N] fp32 -> wT [N,K] bf16. 32x32 LDS tile.
// ---------------------------------------------------------------------------
__global__ __launch_bounds__(256) void transpose_cast(
    const float* __restrict__ w, __bf16* __restrict__ wt, int K, int N) {
  __shared__ float sh[32][33];
  const int n0 = blockIdx.x * 32, k0 = blockIdx.y * 32;
  const int tx = threadIdx.x, ty = threadIdx.y;  // 32 x 8
#pragma unroll
  for (int i = 0; i < 4; ++i)
    sh[ty + i * 8][tx] = w[(size_t)(k0 + ty + i * 8) * N + n0 + tx];
  __syncthreads();
#pragma unroll
  for (int i = 0; i < 4; ++i)
    wt[(size_t)(n0 + ty + i * 8) * K + k0 + tx] = (__bf16)sh[tx][ty + i * 8];
}

// ---------------------------------------------------------------------------
// BF16 MFMA GEMM (m97 structure): C[M,N] = A[M,K] @ B[K,N], B given as
// Bt[N,K]. 128x128 tile, BK=32, 4 waves (2x2). Epilogue bf16 or fp32+bias.
// ---------------------------------------------------------------------------
template <bool BF16OUT>
__global__ __launch_bounds__(256) void gemm_bf16_kernel(
    const __bf16* __restrict__ A, const __bf16* __restrict__ Bt,
    const float* __restrict__ bias, void* __restrict__ Cout,
    int M, int N, int K) {
  __shared__ __align__(16) __bf16 As[128 * 32];
  __shared__ __align__(16) __bf16 Bs[128 * 32];
  const int tid  = threadIdx.x;
  const int w    = tid >> 6;
  const int lane = tid & 63;
  const int quad = lane >> 4;
  const int lr   = lane & 15;
  const int wr   = w >> 1, wc = w & 1;
  const int mBase = blockIdx.y * 128, nBase = blockIdx.x * 128;

  f32x4 acc[4][4] = {};

  const int srow = lane >> 2;
  const int sk8  = (lane & 3) * 8;
  const __bf16* aSrc0 = A  + (size_t)(mBase + w * 32 + srow) * K + sk8;
  const __bf16* aSrc1 = aSrc0 + (size_t)16 * K;
  const __bf16* bSrc0 = Bt + (size_t)(nBase + w * 32 + srow) * K + sk8;
  const __bf16* bSrc1 = bSrc0 + (size_t)16 * K;
  __bf16* aDst0 = &As[(w * 32 + 0) * 32];
  __bf16* aDst1 = &As[(w * 32 + 16) * 32];
  __bf16* bDst0 = &Bs[(w * 32 + 0) * 32];
  __bf16* bDst1 = &Bs[(w * 32 + 16) * 32];

  for (int k0 = 0; k0 < K; k0 += 32) {
    __syncthreads();
    async16(aSrc0 + k0, aDst0);
    async16(aSrc1 + k0, aDst1);
    async16(bSrc0 + k0, bDst0);
    async16(bSrc1 + k0, bDst1);
    __syncthreads();

    bf16x8 af[4], bfr[4];
#pragma unroll
    for (int mt = 0; mt < 4; ++mt)
      af[mt] = *reinterpret_cast<const bf16x8*>(
          &As[(wr * 64 + mt * 16 + lr) * 32 + quad * 8]);
#pragma unroll
    for (int nt = 0; nt < 4; ++nt)
      bfr[nt] = *reinterpret_cast<const bf16x8*>(
          &Bs[(wc * 64 + nt * 16 + lr) * 32 + quad * 8]);
#pragma unroll
    for (int mt = 0; mt < 4; ++mt)
#pragma unroll
      for (int nt = 0; nt < 4; ++nt)
        acc[mt][nt] = __builtin_amdgcn_mfma_f32_16x16x32_bf16(
            af[mt], bfr[nt], acc[mt][nt], 0, 0, 0);
  }

#pragma unroll
  for (int mt = 0; mt < 4; ++mt) {
#pragma unroll
    for (int nt = 0; nt < 4; ++nt) {
      const int col = nBase + wc * 64 + nt * 16 + lr;
#pragma unroll
      for (int r = 0; r < 4; ++r) {
        const size_t row = (size_t)(mBase + wr * 64 + mt * 16 + quad * 4 + r);
        if (BF16OUT) {
          ((__bf16*)Cout)[row * N + col] = (__bf16)acc[mt][nt][r];
        } else {
          ((float*)Cout)[row * N + col] = acc[mt][nt][r] + bias[col];
        }
      }
    }
  }
}

// ---------------------------------------------------------------------------
// Swizzle K and V into fragment-linear global layouts (per (bh, kt) 64-key
// tile), so flash can load MFMA operands with coalesced b128 reads:
//  kF[(hb*32+kt)*8 + f][lane][j]  (bf16) f=nt*2+kc:
//      K[key=nt*16+(lane&15)][d=kc*32+(lane>>4)*8+j]      (A-frag, 16x16x32)
//  vF[(hb*32+kt)*8 + g][lane][j]  (f16)  g=nt*2+ph, j=0..7:
//      V[key=nt*16+(lane>>4)*4+(j&3)][d=(ph*2+(j>>2))*16+(lane&15)] (B-frags)
// ---------------------------------------------------------------------------
__global__ __launch_bounds__(256) void swizzle_kv(
    const __bf16* __restrict__ qkv, __bf16* __restrict__ kF,
    _Float16* __restrict__ vF) {
  const int kt = blockIdx.x;   // 0..31
  const int hb = blockIdx.y;   // 0..47
  const int h = hb % NHEAD, b = hb / NHEAD;
  const int tid = threadIdx.x;

  __shared__ __align__(16) __bf16 Ksh[64][72];   // row stride 144B (16B-mult)
  __shared__ __align__(16) _Float16 Vsh[64][72];

  const int sr = tid >> 3;          // 0..31
  const int sc = (tid & 7) * 8;     // 0,8,..56
  const __bf16* kbase = qkv + (size_t)(b * SEQ + kt * 64) * QKVC + CDIM + h * HDIM;
  const __bf16* vbase = kbase + CDIM;

#pragma unroll
  for (int rr = 0; rr < 2; ++rr) {
    const int row = sr + rr * 32;
    bf16x8 kv = *reinterpret_cast<const bf16x8*>(kbase + (size_t)row * QKVC + sc);
    *reinterpret_cast<bf16x8*>(&Ksh[row][sc]) = kv;
    bf16x8 vv = *reinterpret_cast<const bf16x8*>(vbase + (size_t)row * QKVC + sc);
    f16x8 vf;
#pragma unroll
    for (int j = 0; j < 8; ++j) vf[j] = (_Float16)(float)vv[j];
    *reinterpret_cast<f16x8*>(&Vsh[row][sc]) = vf;
  }
  __syncthreads();

  const size_t tileOff = ((size_t)(hb * 32 + kt)) * 4096;

#pragma unroll
  for (int ss = 0; ss < 2; ++ss) {
    const int s = tid + ss * 256;
    const int f = s >> 6, lane = s & 63;
    const int nt = f >> 1, kc = f & 1;
    const int lq = lane >> 4, ll = lane & 15;
    bf16x8 frag = *reinterpret_cast<const bf16x8*>(
        &Ksh[nt * 16 + ll][kc * 32 + lq * 8]);
    *reinterpret_cast<bf16x8*>(&kF[tileOff + (size_t)f * 512 + lane * 8]) = frag;
  }
#pragma unroll
  for (int ss = 0; ss < 2; ++ss) {
    const int s = tid + ss * 256;
    const int g = s >> 6, lane = s & 63;
    const int nt = g >> 1, ph = g & 1;
    const int lq = lane >> 4, ll = lane & 15;
    f16x8 frag;
#pragma unroll
    for (int j = 0; j < 8; ++j)
      frag[j] = Vsh[nt * 16 + lq * 4 + (j & 3)][(ph * 2 + (j >> 2)) * 16 + ll];
    *reinterpret_cast<f16x8*>(&vF[tileOff + (size_t)g * 512 + lane * 8]) = frag;
  }
}

// ---------------------------------------------------------------------------
// Flash attention, k-split x4. One BLOCK per (hb, q-tile); wave w handles
// k-tiles w, w+4, ... (no-max softmax is linear in k-tiles -> partial (O,l)
// combine additively). Register pipeline identical to R7. End-of-block:
// 2-round LDS tree reduction, wave 0 normalizes and stores.
// __launch_bounds__(256,2): the (256,3) bound in R8 forced the allocator to
// ~170 VGPRs and spilled the 80-reg accumulator set to scratch (WRITE_SIZE
// 12->93MB, FETCH 18->106MB). (256,2) compiled this body spill-free at 104
// VGPRs in R7; residency can still reach 4 blocks/CU if VGPRs allow.
// ---------------------------------------------------------------------------
__global__ __launch_bounds__(256, 2) void flash_mfma_kernel(
    const __bf16* __restrict__ qkv, const __bf16* __restrict__ kF,
    const _Float16* __restrict__ vF, __bf16* __restrict__ out) {
  const int bid  = blockIdx.x;     // 1536 blocks
  const int tid  = threadIdx.x;
  const int w    = tid >> 6;
  const int lane = tid & 63;
  const int quad = lane >> 4;
  const int lr   = lane & 15;

  const int x   = bid & 7;         // XCD (dispatch round-robins %8)
  const int g   = bid >> 3;        // 0..191
  const int qt  = 31 - (g / 6);    // longest-first within each XCD
  const int hb  = x * 6 + (g % 6);
  const int h   = hb % NHEAD, b = hb / NHEAD;

  __shared__ __align__(16) float Red[2][64 * 80];  // 2 x 20 KB partial bufs

  // ---- Q B-frags (64 q), scale = D^-0.5 * log2(e) ----
  bf16x8 qf[4][2];
  {
    const float qs = 0.125f * 1.44269504088896f;
    const __bf16* qp = qkv + (size_t)(b * SEQ + qt * 64) * QKVC + h * HDIM;
#pragma unroll
    for (int qg = 0; qg < 4; ++qg)
#pragma unroll
      for (int kc = 0; kc < 2; ++kc) {
        bf16x8 qr = *reinterpret_cast<const bf16x8*>(
            qp + (size_t)(qg * 16 + lr) * QKVC + kc * 32 + quad * 8);
        bf16x8 f;
#pragma unroll
        for (int j = 0; j < 8; ++j) f[j] = (__bf16)((float)qr[j] * qs);
        qf[qg][kc] = f;
      }
  }

  f32x4 O[4][4] = {};   // [qg][dt], D-layout: row(quad*4+r)=q_lo, col(lr)=d_lo
  f32x4 O4[4] = {};     // row-sums l per qg, same row layout

  const __bf16*   kT = kF + ((size_t)(hb * 32)) * 4096 + lane * 8;
  const _Float16* vT = vF + ((size_t)(hb * 32)) * 4096 + lane * 8;
  const f16x4 vones = {(_Float16)1.f, (_Float16)1.f, (_Float16)1.f, (_Float16)1.f};

  for (int kt = w; kt <= qt; kt += 4) {
    bf16x8 kf[8];
    f16x8  vf8[8];
#pragma unroll
    for (int f = 0; f < 8; ++f)
      kf[f] = *reinterpret_cast<const bf16x8*>(kT + (size_t)kt * 4096 + f * 512);
#pragma unroll
    for (int gg = 0; gg < 8; ++gg)
      vf8[gg] = *reinterpret_cast<const f16x8*>(vT + (size_t)kt * 4096 + gg * 512);

#pragma unroll
    for (int nt = 0; nt < 4; ++nt) {
      f32x4 s[4];
#pragma unroll
      for (int qg = 0; qg < 4; ++qg) {
        f32x4 acc = (f32x4){0.f, 0.f, 0.f, 0.f};
        acc = __builtin_amdgcn_mfma_f32_16x16x32_bf16(kf[nt * 2 + 0], qf[qg][0], acc, 0, 0, 0);
        acc = __builtin_amdgcn_mfma_f32_16x16x32_bf16(kf[nt * 2 + 1], qf[qg][1], acc, 0, 0, 0);
        s[qg] = acc;
      }
      if (kt == qt) {  // diagonal tile: causal mask
#pragma unroll
        for (int qg = 0; qg < 4; ++qg)
#pragma unroll
          for (int r = 0; r < 4; ++r)
            if (nt * 16 + quad * 4 + r > qg * 16 + lr) s[qg][r] = -1e30f;
      }
      f16x4 pa[4];
#pragma unroll
      for (int qg = 0; qg < 4; ++qg) {
        f16x4 t;
#pragma unroll
        for (int r = 0; r < 4; ++r)
          t[r] = (_Float16)__builtin_amdgcn_exp2f(s[qg][r]);
        pa[qg] = t;
      }
#pragma unroll
      for (int qg = 0; qg < 4; ++qg)
        O4[qg] = __builtin_amdgcn_mfma_f32_16x16x16f16(pa[qg], vones, O4[qg], 0, 0, 0);
#pragma unroll
      for (int dt = 0; dt < 4; ++dt) {
        const f16x8 vv = vf8[nt * 2 + (dt >> 1)];
        f16x4 vb;
#pragma unroll
        for (int j = 0; j < 4; ++j) vb[j] = vv[(dt & 1) * 4 + j];
#pragma unroll
        for (int qg = 0; qg < 4; ++qg)
          O[qg][dt] = __builtin_amdgcn_mfma_f32_16x16x16f16(pa[qg], vb, O[qg][dt], 0, 0, 0);
      }
    }
  }

  // ---- 2-round additive reduction: 20 f32x4 per lane (16 O + 4 O4) ----
  if (w == 1 || w == 3) {
    float* dst = Red[w >> 1];
#pragma unroll
    for (int qg = 0; qg < 4; ++qg)
#pragma unroll
      for (int dt = 0; dt < 4; ++dt)
        *reinterpret_cast<f32x4*>(&dst[((qg * 4 + dt) * 64 + lane) * 4]) = O[qg][dt];
#pragma unroll
    for (int qg = 0; qg < 4; ++qg)
      *reinterpret_cast<f32x4*>(&dst[((16 + qg) * 64 + lane) * 4]) = O4[qg];
  }
  __syncthreads();
  if (w == 0 || w == 2) {
    const float* src = Red[w >> 1];
#pragma unroll
    for (int qg = 0; qg < 4; ++qg)
#pragma unroll
      for (int dt = 0; dt < 4; ++dt)
        O[qg][dt] += *reinterpret_cast<const f32x4*>(&src[((qg * 4 + dt) * 64 + lane) * 4]);
#pragma unroll
    for (int qg = 0; qg < 4; ++qg)
      O4[qg] += *reinterpret_cast<const f32x4*>(&src[((16 + qg) * 64 + lane) * 4]);
  }
  __syncthreads();
  if (w == 2) {
    float* dst = Red[0];
#pragma unroll
    for (int qg = 0; qg < 4; ++qg)
#pragma unroll
      for (int dt = 0; dt < 4; ++dt)
        *reinterpret_cast<f32x4*>(&dst[((qg * 4 + dt) * 64 + lane) * 4]) = O[qg][dt];
#pragma unroll
    for (int qg = 0; qg < 4; ++qg)
      *reinterpret_cast<f32x4*>(&dst[((16 + qg) * 64 + lane) * 4]) = O4[qg];
  }
  __syncthreads();
  if (w == 0) {
    const float* src = Red[0];
#pragma unroll
    for (int qg = 0; qg < 4; ++qg)
#pragma unroll
      for (int dt = 0; dt < 4; ++dt)
        O[qg][dt] += *reinterpret_cast<const f32x4*>(&src[((qg * 4 + dt) * 64 + lane) * 4]);
#pragma unroll
    for (int qg = 0; qg < 4; ++qg)
      O4[qg] += *reinterpret_cast<const f32x4*>(&src[((16 + qg) * 64 + lane) * 4]);

    // ---- epilogue: O/l, store bf16 ----
    __bf16* obase = out + (size_t)(b * SEQ + qt * 64) * CDIM + h * HDIM;
#pragma unroll
    for (int qg = 0; qg < 4; ++qg) {
      float linv[4];
#pragma unroll
      for (int r = 0; r < 4; ++r) linv[r] = 1.f / O4[qg][r];
#pragma unroll
      for (int dt = 0; dt < 4; ++dt)
#pragma unroll
        for (int r = 0; r < 4; ++r)
          obase[(size_t)(qg * 16 + quad * 4 + r) * CDIM + dt * 16 + lr] =
              (__bf16)(O[qg][dt][r] * linv[r]);
    }
  }
}

// ---------------------------------------------------------------------------
extern "C" void kernel_launch(void* const* d_in, const int* in_sizes, int n_in,
                              void* d_out, int out_size, void* d_ws, size_t ws_size,
                              hipStream_t stream) {
  const float* x      = (const float*)d_in[0];
  const float* w_qkv  = (const float*)d_in[1];
  const float* w_proj = (const float*)d_in[2];
  const float* b_proj = (const float*)d_in[3];
  float* out = (float*)d_out;

  __bf16* qkv    = (__bf16*)d_ws;                       // [8192,2304]
  __bf16* attnb  = qkv + (size_t)MROWS * QKVC;          // [8192,768]
  __bf16* xb     = attnb + (size_t)MROWS * CDIM;        // [8192,768]
  __bf16* wqkvT  = xb + (size_t)MROWS * CDIM;           // [2304,768]
  __bf16* wprojT = wqkvT + (size_t)QKVC * CDIM;         // [768,768]
  __bf16* kFb    = wprojT + (size_t)CDIM * CDIM;        // [48*32*4096] bf16
  _Float16* vFb  = (_Float16*)(kFb + (size_t)48 * 32 * 4096);  // same size f16

  cast_f32_bf16<<<dim3((MROWS * CDIM / 8 + 255) / 256), dim3(256), 0, stream>>>(
      x, xb, MROWS * CDIM / 8);
  transpose_cast<<<dim3(QKVC / 32, CDIM / 32), dim3(32, 8), 0, stream>>>(
      w_qkv, wqkvT, CDIM, QKVC);
  transpose_cast<<<dim3(CDIM / 32, CDIM / 32), dim3(32, 8), 0, stream>>>(
      w_proj, wprojT, CDIM, CDIM);

  // 1) QKV projection (bf16 MFMA, bf16 out)
  gemm_bf16_kernel<true><<<dim3(QKVC / 128, MROWS / 128), dim3(256), 0, stream>>>(
      xb, wqkvT, nullptr, qkv, MROWS, QKVC, CDIM);

  // 1b) K/V fragment swizzle for flash
  swizzle_kv<<<dim3(32, 48), dim3(256), 0, stream>>>(qkv, kFb, vFb);

  // 2) causal flash attention (k-split x4, additive reduction)
  flash_mfma_kernel<<<dim3(1536), dim3(256), 0, stream>>>(qkv, kFb, vFb, attnb);

  // 3) output projection (bf16 MFMA, fp32 + bias out)
  gemm_bf16_kernel<false><<<dim3(CDIM / 128, MROWS / 128), dim3(256), 0, stream>>>(
      attnb, wprojT, b_proj, out, MROWS, CDIM, CDIM);
}

// Round 10
// 195.293 us; speedup vs baseline: 1.2681x; 1.0691x over previous
//
#include <hip/hip_runtime.h>
#include <hip/hip_bf16.h>
#include <math.h>

// Problem constants: B=4, N=2048, C=768, H=12, D=64
#define BATCH 4
#define SEQ   2048
#define CDIM  768
#define NHEAD 12
#define HDIM  64
#define MROWS (BATCH*SEQ)      // 8192
#define QKVC  (3*CDIM)         // 2304

typedef __bf16    bf16x8 __attribute__((ext_vector_type(8)));
typedef _Float16  f16x8  __attribute__((ext_vector_type(8)));
typedef _Float16  f16x4  __attribute__((ext_vector_type(4)));
typedef float     f32x4  __attribute__((ext_vector_type(4)));

__device__ __forceinline__ void async16(const void* g, void* l) {
  __builtin_amdgcn_global_load_lds(
      (const __attribute__((address_space(1))) void*)g,
      (__attribute__((address_space(3))) void*)l, 16, 0, 0);
}

// ---------------------------------------------------------------------------
// Elementwise fp32 -> bf16 cast, 8 elems/thread.
// ---------------------------------------------------------------------------
__global__ __launch_bounds__(256) void cast_f32_bf16(
    const float* __restrict__ in, __bf16* __restrict__ out, int n8) {
  int i = blockIdx.x * 256 + threadIdx.x;
  if (i >= n8) return;
  float4 a = reinterpret_cast<const float4*>(in)[i * 2];
  float4 b = reinterpret_cast<const float4*>(in)[i * 2 + 1];
  bf16x8 o;
  o[0] = (__bf16)a.x; o[1] = (__bf16)a.y; o[2] = (__bf16)a.z; o[3] = (__bf16)a.w;
  o[4] = (__bf16)b.x; o[5] = (__bf16)b.y; o[6] = (__bf16)b.z; o[7] = (__bf16)b.w;
  reinterpret_cast<bf16x8*>(out)[i] = o;
}

// ---------------------------------------------------------------------------
// Transpose-cast: w [K,N] fp32 -> wT [N,K] bf16. 32x32 LDS tile.
// ---------------------------------------------------------------------------
__global__ __launch_bounds__(256) void transpose_cast(
    const float* __restrict__ w, __bf16* __restrict__ wt, int K, int N) {
  __shared__ float sh[32][33];
  const int n0 = blockIdx.x * 32, k0 = blockIdx.y * 32;
  const int tx = threadIdx.x, ty = threadIdx.y;  // 32 x 8
#pragma unroll
  for (int i = 0; i < 4; ++i)
    sh[ty + i * 8][tx] = w[(size_t)(k0 + ty + i * 8) * N + n0 + tx];
  __syncthreads();
#pragma unroll
  for (int i = 0; i < 4; ++i)
    wt[(size_t)(n0 + ty + i * 8) * K + k0 + tx] = (__bf16)sh[tx][ty + i * 8];
}

// ---------------------------------------------------------------------------
// BF16 MFMA GEMM, BK=64 (two BK=32 half-tiles per barrier -> half the
// barrier drains of the m97 structure; LDS layout per half identical to the
// proven conflict-benign 64B-row-stride layout). 128x128 tile, 4 waves (2x2).
// MODE 0: fused QKV epilogue -- Q cols (<768) stored plain bf16 into qkv
//   (stride N=QKVC); K cols scattered directly into kF A-frag layout; V cols
//   packed f16x4 into vF B-frag layout (replaces the swizzle_kv kernel and
//   its ~50MB HBM relayout round-trip).
// MODE 1: fp32 + bias epilogue (proj).
// Frag layouts (must match flash reads):
//  kF[tile + f*512 + lane*8 + j] = K[key=nt*16+(lane&15)][d=kc*32+(lane>>4)*8+j], f=nt*2+kc
//  vF[tile + g*512 + lane*8 + j] = V[key=nt*16+(lane>>4)*4+(j&3)][d=(ph*2+(j>>2))*16+(lane&15)], g=nt*2+ph
// ---------------------------------------------------------------------------
template <int MODE>
__global__ __launch_bounds__(256) void gemm_bk64_kernel(
    const __bf16* __restrict__ A, const __bf16* __restrict__ Bt,
    const float* __restrict__ bias, void* __restrict__ Cout,
    __bf16* __restrict__ kF, _Float16* __restrict__ vF,
    int M, int N, int K) {
  __shared__ __align__(16) __bf16 As[2][128 * 32];
  __shared__ __align__(16) __bf16 Bs[2][128 * 32];
  const int tid  = threadIdx.x;
  const int w    = tid >> 6;
  const int lane = tid & 63;
  const int quad = lane >> 4;
  const int lr   = lane & 15;
  const int wr   = w >> 1, wc = w & 1;
  const int mBase = blockIdx.y * 128, nBase = blockIdx.x * 128;

  f32x4 acc[4][4] = {};

  const int srow = lane >> 2;
  const int sk8  = (lane & 3) * 8;
  const __bf16* aSrc0 = A  + (size_t)(mBase + w * 32 + srow) * K + sk8;
  const __bf16* aSrc1 = aSrc0 + (size_t)16 * K;
  const __bf16* bSrc0 = Bt + (size_t)(nBase + w * 32 + srow) * K + sk8;
  const __bf16* bSrc1 = bSrc0 + (size_t)16 * K;

  for (int k0 = 0; k0 < K; k0 += 64) {
    __syncthreads();
#pragma unroll
    for (int kh = 0; kh < 2; ++kh) {
      async16(aSrc0 + k0 + kh * 32, &As[kh][(w * 32 + 0) * 32]);
      async16(aSrc1 + k0 + kh * 32, &As[kh][(w * 32 + 16) * 32]);
      async16(bSrc0 + k0 + kh * 32, &Bs[kh][(w * 32 + 0) * 32]);
      async16(bSrc1 + k0 + kh * 32, &Bs[kh][(w * 32 + 16) * 32]);
    }
    __syncthreads();

#pragma unroll
    for (int kh = 0; kh < 2; ++kh) {
      bf16x8 af[4], bfr[4];
#pragma unroll
      for (int mt = 0; mt < 4; ++mt)
        af[mt] = *reinterpret_cast<const bf16x8*>(
            &As[kh][(wr * 64 + mt * 16 + lr) * 32 + quad * 8]);
#pragma unroll
      for (int nt = 0; nt < 4; ++nt)
        bfr[nt] = *reinterpret_cast<const bf16x8*>(
            &Bs[kh][(wc * 64 + nt * 16 + lr) * 32 + quad * 8]);
#pragma unroll
      for (int mt = 0; mt < 4; ++mt)
#pragma unroll
        for (int nt = 0; nt < 4; ++nt)
          acc[mt][nt] = __builtin_amdgcn_mfma_f32_16x16x32_bf16(
              af[mt], bfr[nt], acc[mt][nt], 0, 0, 0);
    }
  }

  if (MODE == 1) {
    // proj epilogue: fp32 + bias
#pragma unroll
    for (int mt = 0; mt < 4; ++mt)
#pragma unroll
      for (int nt = 0; nt < 4; ++nt) {
        const int col = nBase + wc * 64 + nt * 16 + lr;
#pragma unroll
        for (int r = 0; r < 4; ++r) {
          const size_t row = (size_t)(mBase + wr * 64 + mt * 16 + quad * 4 + r);
          ((float*)Cout)[row * N + col] = acc[mt][nt][r] + bias[col];
        }
      }
  } else {
    const int region = nBase / CDIM;   // 0=Q, 1=K, 2=V (block-uniform)
    if (region == 0) {
      // Q: plain bf16 into qkv (stride N)
#pragma unroll
      for (int mt = 0; mt < 4; ++mt)
#pragma unroll
        for (int nt = 0; nt < 4; ++nt) {
          const int col = nBase + wc * 64 + nt * 16 + lr;
#pragma unroll
          for (int r = 0; r < 4; ++r) {
            const size_t row = (size_t)(mBase + wr * 64 + mt * 16 + quad * 4 + r);
            ((__bf16*)Cout)[row * N + col] = (__bf16)acc[mt][nt][r];
          }
        }
    } else {
      const int bb  = mBase >> 11;                         // batch
      const int ktB = ((mBase & 2047) >> 6) + wr;          // 64-key tile
      const int hq  = ((nBase % CDIM) + wc * 64) >> 6;     // head
      const size_t tile = ((size_t)(bb * NHEAD + hq) * 32 + ktB) * 4096;
      if (region == 1) {
        // K scatter: key=mt*16+quad*4+r, d=nt*16+lr
#pragma unroll
        for (int mt = 0; mt < 4; ++mt)
#pragma unroll
          for (int nt = 0; nt < 4; ++nt) {
            const size_t base = tile + (size_t)(mt * 2 + (nt >> 1)) * 512
                + (((nt & 1) * 2 + (lr >> 3)) * 16) * 8 + (lr & 7);
#pragma unroll
            for (int r = 0; r < 4; ++r)
              kF[base + (quad * 4 + r) * 8] = (__bf16)acc[mt][nt][r];
          }
      } else {
        // V pack: key=mt*16+quad*4+r, d=nt*16+lr; r=0..3 -> one f16x4
#pragma unroll
        for (int mt = 0; mt < 4; ++mt)
#pragma unroll
          for (int nt = 0; nt < 4; ++nt) {
            f16x4 vp;
#pragma unroll
            for (int r = 0; r < 4; ++r) vp[r] = (_Float16)acc[mt][nt][r];
            *reinterpret_cast<f16x4*>(
                &vF[tile + (size_t)(mt * 2 + (nt >> 1)) * 512
                    + (quad * 16 + lr) * 8 + (nt & 1) * 4]) = vp;
          }
      }
    }
  }
}

// ---------------------------------------------------------------------------
// Flash attention, k-split x4 (unchanged from R9). One BLOCK per (hb, qt);
// wave w handles k-tiles w, w+4, ... (no-max softmax is linear in k-tiles ->
// partials combine additively). LDS-free per-k-tile register pipeline on
// pre-swizzled kF/vF frags; S^T trick; MFMA row-sum. 2-round LDS reduction.
// (256,2): (256,3) caused accumulator spill (R8: WRITE 12->93MB).
// ---------------------------------------------------------------------------
__global__ __launch_bounds__(256, 2) void flash_mfma_kernel(
    const __bf16* __restrict__ qkv, const __bf16* __restrict__ kF,
    const _Float16* __restrict__ vF, __bf16* __restrict__ out) {
  const int bid  = blockIdx.x;     // 1536 blocks
  const int tid  = threadIdx.x;
  const int w    = tid >> 6;
  const int lane = tid & 63;
  const int quad = lane >> 4;
  const int lr   = lane & 15;

  const int x   = bid & 7;         // XCD (dispatch round-robins %8)
  const int g   = bid >> 3;        // 0..191
  const int qt  = 31 - (g / 6);    // longest-first within each XCD
  const int hb  = x * 6 + (g % 6);
  const int h   = hb % NHEAD, b = hb / NHEAD;

  __shared__ __align__(16) float Red[2][64 * 80];  // 2 x 20 KB partial bufs

  // ---- Q B-frags (64 q), scale = D^-0.5 * log2(e) ----
  bf16x8 qf[4][2];
  {
    const float qs = 0.125f * 1.44269504088896f;
    const __bf16* qp = qkv + (size_t)(b * SEQ + qt * 64) * QKVC + h * HDIM;
#pragma unroll
    for (int qg = 0; qg < 4; ++qg)
#pragma unroll
      for (int kc = 0; kc < 2; ++kc) {
        bf16x8 qr = *reinterpret_cast<const bf16x8*>(
            qp + (size_t)(qg * 16 + lr) * QKVC + kc * 32 + quad * 8);
        bf16x8 f;
#pragma unroll
        for (int j = 0; j < 8; ++j) f[j] = (__bf16)((float)qr[j] * qs);
        qf[qg][kc] = f;
      }
  }

  f32x4 O[4][4] = {};   // [qg][dt], D-layout: row(quad*4+r)=q_lo, col(lr)=d_lo
  f32x4 O4[4] = {};     // row-sums l per qg, same row layout

  const __bf16*   kT = kF + ((size_t)(hb * 32)) * 4096 + lane * 8;
  const _Float16* vT = vF + ((size_t)(hb * 32)) * 4096 + lane * 8;
  const f16x4 vones = {(_Float16)1.f, (_Float16)1.f, (_Float16)1.f, (_Float16)1.f};

  for (int kt = w; kt <= qt; kt += 4) {
    bf16x8 kf[8];
    f16x8  vf8[8];
#pragma unroll
    for (int f = 0; f < 8; ++f)
      kf[f] = *reinterpret_cast<const bf16x8*>(kT + (size_t)kt * 4096 + f * 512);
#pragma unroll
    for (int gg = 0; gg < 8; ++gg)
      vf8[gg] = *reinterpret_cast<const f16x8*>(vT + (size_t)kt * 4096 + gg * 512);

#pragma unroll
    for (int nt = 0; nt < 4; ++nt) {
      f32x4 s[4];
#pragma unroll
      for (int qg = 0; qg < 4; ++qg) {
        f32x4 acc = (f32x4){0.f, 0.f, 0.f, 0.f};
        acc = __builtin_amdgcn_mfma_f32_16x16x32_bf16(kf[nt * 2 + 0], qf[qg][0], acc, 0, 0, 0);
        acc = __builtin_amdgcn_mfma_f32_16x16x32_bf16(kf[nt * 2 + 1], qf[qg][1], acc, 0, 0, 0);
        s[qg] = acc;
      }
      if (kt == qt) {  // diagonal tile: causal mask
#pragma unroll
        for (int qg = 0; qg < 4; ++qg)
#pragma unroll
          for (int r = 0; r < 4; ++r)
            if (nt * 16 + quad * 4 + r > qg * 16 + lr) s[qg][r] = -1e30f;
      }
      f16x4 pa[4];
#pragma unroll
      for (int qg = 0; qg < 4; ++qg) {
        f16x4 t;
#pragma unroll
        for (int r = 0; r < 4; ++r)
          t[r] = (_Float16)__builtin_amdgcn_exp2f(s[qg][r]);
        pa[qg] = t;
      }
#pragma unroll
      for (int qg = 0; qg < 4; ++qg)
        O4[qg] = __builtin_amdgcn_mfma_f32_16x16x16f16(pa[qg], vones, O4[qg], 0, 0, 0);
#pragma unroll
      for (int dt = 0; dt < 4; ++dt) {
        const f16x8 vv = vf8[nt * 2 + (dt >> 1)];
        f16x4 vb;
#pragma unroll
        for (int j = 0; j < 4; ++j) vb[j] = vv[(dt & 1) * 4 + j];
#pragma unroll
        for (int qg = 0; qg < 4; ++qg)
          O[qg][dt] = __builtin_amdgcn_mfma_f32_16x16x16f16(pa[qg], vb, O[qg][dt], 0, 0, 0);
      }
    }
  }

  // ---- 2-round additive reduction: 20 f32x4 per lane (16 O + 4 O4) ----
  if (w == 1 || w == 3) {
    float* dst = Red[w >> 1];
#pragma unroll
    for (int qg = 0; qg < 4; ++qg)
#pragma unroll
      for (int dt = 0; dt < 4; ++dt)
        *reinterpret_cast<f32x4*>(&dst[((qg * 4 + dt) * 64 + lane) * 4]) = O[qg][dt];
#pragma unroll
    for (int qg = 0; qg < 4; ++qg)
      *reinterpret_cast<f32x4*>(&dst[((16 + qg) * 64 + lane) * 4]) = O4[qg];
  }
  __syncthreads();
  if (w == 0 || w == 2) {
    const float* src = Red[w >> 1];
#pragma unroll
    for (int qg = 0; qg < 4; ++qg)
#pragma unroll
      for (int dt = 0; dt < 4; ++dt)
        O[qg][dt] += *reinterpret_cast<const f32x4*>(&src[((qg * 4 + dt) * 64 + lane) * 4]);
#pragma unroll
    for (int qg = 0; qg < 4; ++qg)
      O4[qg] += *reinterpret_cast<const f32x4*>(&src[((16 + qg) * 64 + lane) * 4]);
  }
  __syncthreads();
  if (w == 2) {
    float* dst = Red[0];
#pragma unroll
    for (int qg = 0; qg < 4; ++qg)
#pragma unroll
      for (int dt = 0; dt < 4; ++dt)
        *reinterpret_cast<f32x4*>(&dst[((qg * 4 + dt) * 64 + lane) * 4]) = O[qg][dt];
#pragma unroll
    for (int qg = 0; qg < 4; ++qg)
      *reinterpret_cast<f32x4*>(&dst[((16 + qg) * 64 + lane) * 4]) = O4[qg];
  }
  __syncthreads();
  if (w == 0) {
    const float* src = Red[0];
#pragma unroll
    for (int qg = 0; qg < 4; ++qg)
#pragma unroll
      for (int dt = 0; dt < 4; ++dt)
        O[qg][dt] += *reinterpret_cast<const f32x4*>(&src[((qg * 4 + dt) * 64 + lane) * 4]);
#pragma unroll
    for (int qg = 0; qg < 4; ++qg)
      O4[qg] += *reinterpret_cast<const f32x4*>(&src[((16 + qg) * 64 + lane) * 4]);

    // ---- epilogue: O/l, store bf16 ----
    __bf16* obase = out + (size_t)(b * SEQ + qt * 64) * CDIM + h * HDIM;
#pragma unroll
    for (int qg = 0; qg < 4; ++qg) {
      float linv[4];
#pragma unroll
      for (int r = 0; r < 4; ++r) linv[r] = 1.f / O4[qg][r];
#pragma unroll
      for (int dt = 0; dt < 4; ++dt)
#pragma unroll
        for (int r = 0; r < 4; ++r)
          obase[(size_t)(qg * 16 + quad * 4 + r) * CDIM + dt * 16 + lr] =
              (__bf16)(O[qg][dt][r] * linv[r]);
    }
  }
}

// ---------------------------------------------------------------------------
extern "C" void kernel_launch(void* const* d_in, const int* in_sizes, int n_in,
                              void* d_out, int out_size, void* d_ws, size_t ws_size,
                              hipStream_t stream) {
  const float* x      = (const float*)d_in[0];
  const float* w_qkv  = (const float*)d_in[1];
  const float* w_proj = (const float*)d_in[2];
  const float* b_proj = (const float*)d_in[3];
  float* out = (float*)d_out;

  __bf16* qkv    = (__bf16*)d_ws;                       // [8192,2304] (Q region used)
  __bf16* attnb  = qkv + (size_t)MROWS * QKVC;          // [8192,768]
  __bf16* xb     = attnb + (size_t)MROWS * CDIM;        // [8192,768]
  __bf16* wqkvT  = xb + (size_t)MROWS * CDIM;           // [2304,768]
  __bf16* wprojT = wqkvT + (size_t)QKVC * CDIM;         // [768,768]
  __bf16* kFb    = wprojT + (size_t)CDIM * CDIM;        // [48*32*4096] bf16
  _Float16* vFb  = (_Float16*)(kFb + (size_t)48 * 32 * 4096);  // same size f16

  cast_f32_bf16<<<dim3((MROWS * CDIM / 8 + 255) / 256), dim3(256), 0, stream>>>(
      x, xb, MROWS * CDIM / 8);
  transpose_cast<<<dim3(QKVC / 32, CDIM / 32), dim3(32, 8), 0, stream>>>(
      w_qkv, wqkvT, CDIM, QKVC);
  transpose_cast<<<dim3(CDIM / 32, CDIM / 32), dim3(32, 8), 0, stream>>>(
      w_proj, wprojT, CDIM, CDIM);

  // 1) QKV projection, fused epilogue: Q plain + K/V straight into frag layout
  gemm_bk64_kernel<0><<<dim3(QKVC / 128, MROWS / 128), dim3(256), 0, stream>>>(
      xb, wqkvT, nullptr, qkv, kFb, vFb, MROWS, QKVC, CDIM);

  // 2) causal flash attention (k-split x4, additive reduction)
  flash_mfma_kernel<<<dim3(1536), dim3(256), 0, stream>>>(qkv, kFb, vFb, attnb);

  // 3) output projection (fp32 + bias out)
  gemm_bk64_kernel<1><<<dim3(CDIM / 128, MROWS / 128), dim3(256), 0, stream>>>(
      attnb, wprojT, b_proj, out, nullptr, nullptr, MROWS, CDIM, CDIM);
}